// Round 9
// baseline (446.177 us; speedup 1.0000x reference)
//
#include <hip/hip_runtime.h>

#define EPS 1e-6f

typedef _Float16 f16;
typedef __fp16 h16x2 __attribute__((ext_vector_type(2)));
typedef _Float16 f16x4 __attribute__((ext_vector_type(4)));
typedef _Float16 f16x8 __attribute__((ext_vector_type(8)));
typedef float f32x4 __attribute__((ext_vector_type(4)));

__device__ __forceinline__ float tanh_fast(float x) {
    float e = __expf(2.0f * x);
    return 1.0f - 2.0f / (e + 1.0f);
}

// ---------------- kernel 1: W1/W4 fp32 -> f16 (small) ----------------
__global__ __launch_bounds__(256) void convw_kernel(
    const float4* __restrict__ W1, const float4* __restrict__ W4,
    f16x4* __restrict__ Wh1, f16x4* __restrict__ Wh4)
{
    const int stride = gridDim.x * 256;
    for (int i = blockIdx.x * 256 + threadIdx.x; i < 524288; i += stride) {
        const float4* s = (i < 262144) ? W1 : W4;
        f16x4* d       = (i < 262144) ? Wh1 : Wh4;
        int off = i & 262143;
        float4 v = s[off];
        f16x4 o; o[0]=(f16)v.x; o[1]=(f16)v.y; o[2]=(f16)v.z; o[3]=(f16)v.w;
        d[off] = o;
    }
}

// ---------------- kernel 2: gamma/alpha GEMVs, W-reuse over 8 batches ----------------
// block = 4 waves; wave w handles h = hb*4+w for 8 consecutive b (W row cached in regs)
__global__ __launch_bounds__(256) void gamal_kernel(
    const float* __restrict__ inp,
    const float* __restrict__ W2, const float* __restrict__ b2,
    const float* __restrict__ W5, const float* __restrict__ b5,
    float* __restrict__ gamm, float* __restrict__ alph)
{
    const float* W  = blockIdx.y ? W5 : W2;
    const float* bs = blockIdx.y ? b5 : b2;
    float* dst      = blockIdx.y ? alph : gamm;
    int wid = threadIdx.x >> 6, lane = threadIdx.x & 63;
    int hb = blockIdx.x >> 3;          // 0..255
    int bb = blockIdx.x & 7;           // 0..7
    int h = hb * 4 + wid;
    int b0 = bb * 8;
    const float4* wr = (const float4*)(W + (size_t)h * 1024);
    float4 wreg[4];
    #pragma unroll
    for (int j = 0; j < 4; ++j) wreg[j] = wr[lane + 64 * j];
    float bias = bs[h];
    for (int b = b0; b < b0 + 8; ++b) {
        const float4* xr = (const float4*)(inp + (size_t)b * 1024);
        float acc = 0.f;
        #pragma unroll
        for (int j = 0; j < 4; ++j) {
            float4 x4 = xr[lane + 64 * j];
            acc += wreg[j].x * x4.x + wreg[j].y * x4.y + wreg[j].z * x4.z + wreg[j].w * x4.w;
        }
        #pragma unroll
        for (int o = 32; o; o >>= 1) acc += __shfl_xor(acc, o);
        if (lane == 0) dst[b * 1024 + h] = tanh_fast(acc + bias);
    }
}

// ---------------- kernel 3: 128x128xK1024 GEMM, A fp32 reg-staged (fused cvt), W gload_lds ----------------
// Round-6 structure + fused A conversion. loadA(t+1) issued BEFORE compute(t) (latency under MFMA).
// Single 33KB LDS buffer, plain __syncthreads, no inline asm.
__global__ __launch_bounds__(256, 3) void gemm_logits_kernel(
    const float* __restrict__ Ahid, const float* __restrict__ Afld,   // fp32 inputs
    const f16* __restrict__ Wh,      // [2][1024][1024] f16
    const float* __restrict__ b1, const float* __restrict__ b4,
    const float* __restrict__ gamm, const float* __restrict__ alph,
    float* __restrict__ Lpart)       // [2][8][32768]
{
    __shared__ __align__(16) char smA[16384];   // 128 rows x 128 B (f16)
    __shared__ __align__(16) char smW[16384];
    __shared__ float rowpart[128][2];

    const int lin = blockIdx.x;                     // 4096 blocks
    const int gidx = (lin & 7) * 512 + (lin >> 3);  // XCD swizzle, bijective
    const int mat = gidx >> 11;
    const int rem = gidx & 2047;
    const int m_blk = rem >> 3;
    const int nc = rem & 7;
    const int m0 = m_blk << 7;
    const int hc0 = nc << 7;
    const int bidx = m_blk >> 2;

    const float* A = mat ? Afld : Ahid;
    const f16*  W  = Wh + (size_t)mat * 1048576;
    const float* bv = mat ? b4 : b1;
    const float* gv = mat ? alph : gamm;

    const int t = threadIdx.x;
    const int lane = t & 63;
    const int wv = t >> 6;       // 0..3
    const int wr = wv >> 1;      // 0..1
    const int wc = wv & 1;       // 0..1
    const int c16 = lane & 15;
    const int kg = lane >> 4;

    // A staging: 2 threads/row, 32 consecutive floats each
    const int srow = t >> 1;
    const int shalf = t & 1;
    const float* aRow = A + (size_t)(m0 + srow) * 1024 + shalf * 32;

    // W gload_lds pre-swizzled source
    const int lrow = lane >> 3, lslot = lane & 7;
    const int kchunk = lslot ^ lrow;

    const int swzr = (c16 & 7) << 4;
    const int aoffb = (wr * 64 + c16) * 128;
    const int woffb = (wc * 64 + c16) * 128;
    const int kg16 = kg * 16;

    f32x4 acc[4][4];
    #pragma unroll
    for (int i = 0; i < 4; ++i)
        #pragma unroll
        for (int j = 0; j < 4; ++j) acc[i][j] = (f32x4){0.f, 0.f, 0.f, 0.f};

    float4 a_ld[8];
    auto loadA = [&](int kt) {
        const float4* ap = (const float4*)(aRow + kt * 64);
        #pragma unroll
        for (int j = 0; j < 8; ++j) a_ld[j] = ap[j];
    };
    auto writeA = [&]() {
        char* ad = smA + srow * 128;
        const int swzw = (srow & 7) << 4;
        const int wb = shalf * 64;
        #pragma unroll
        for (int j = 0; j < 4; ++j) {
            union { f16x8 v; h16x2 q[4]; } u;
            float4 x = a_ld[2 * j], y = a_ld[2 * j + 1];
            u.q[0] = __builtin_amdgcn_cvt_pkrtz(x.x, x.y);
            u.q[1] = __builtin_amdgcn_cvt_pkrtz(x.z, x.w);
            u.q[2] = __builtin_amdgcn_cvt_pkrtz(y.x, y.y);
            u.q[3] = __builtin_amdgcn_cvt_pkrtz(y.z, y.w);
            *(f16x8*)(ad + ((wb + j * 16) ^ swzw)) = u.v;
        }
    };
    auto gloadW = [&](int kt) {
        #pragma unroll
        for (int j = 0; j < 4; ++j) {
            int r = wv * 32 + j * 8;
            const f16* srcW = W + (size_t)(hc0 + r + lrow) * 1024 + kt * 64 + kchunk * 8;
            __builtin_amdgcn_global_load_lds(
                (const __attribute__((address_space(1))) void*)srcW,
                (__attribute__((address_space(3))) void*)(smW + r * 128), 16, 0, 0);
        }
    };

    loadA(0);
    for (int kt = 0; kt < 16; ++kt) {
        gloadW(kt);
        writeA();            // compiler waits a_ld, cvt -> swizzled ds_write
        __syncthreads();     // drains W gloads + LDS writes
        loadA(kt < 15 ? kt + 1 : 15);   // issue next A loads; latency hides under MFMA

        #pragma unroll
        for (int kk = 0; kk < 2; ++kk) {
            const int ko = (kk * 64 + kg16) ^ swzr;
            f16x8 af[4], wf[4];
            #pragma unroll
            for (int i = 0; i < 4; ++i) af[i] = *(const f16x8*)(smA + aoffb + i * 2048 + ko);
            #pragma unroll
            for (int i = 0; i < 4; ++i) wf[i] = *(const f16x8*)(smW + woffb + i * 2048 + ko);
            #pragma unroll
            for (int ni = 0; ni < 4; ++ni)
                #pragma unroll
                for (int mi = 0; mi < 4; ++mi)
                    acc[mi][ni] = __builtin_amdgcn_mfma_f32_16x16x32_f16(af[mi], wf[ni], acc[mi][ni], 0, 0, 0);
        }
        __syncthreads();     // compute done before next overwrite
    }

    // ---- epilogue: tanh + gamma-dot over this block's 128 cols ----
    float g[4], bb[4];
    #pragma unroll
    for (int ni = 0; ni < 4; ++ni) {
        int h = hc0 + wc * 64 + ni * 16 + c16;
        g[ni]  = gv[(bidx << 10) + h];
        bb[ni] = bv[h];
    }
    #pragma unroll
    for (int mi = 0; mi < 4; ++mi) {
        #pragma unroll
        for (int q = 0; q < 4; ++q) {
            float v = tanh_fast(acc[mi][0][q] + bb[0]) * g[0]
                    + tanh_fast(acc[mi][1][q] + bb[1]) * g[1]
                    + tanh_fast(acc[mi][2][q] + bb[2]) * g[2]
                    + tanh_fast(acc[mi][3][q] + bb[3]) * g[3];
            v += __shfl_xor(v, 1);
            v += __shfl_xor(v, 2);
            v += __shfl_xor(v, 4);
            v += __shfl_xor(v, 8);
            if (c16 == 0)
                rowpart[wr * 64 + mi * 16 + kg * 4 + q][wc] = v;
        }
    }
    __syncthreads();
    if (t < 128)
        Lpart[(size_t)(mat * 8 + nc) * 32768 + m0 + t] = rowpart[t][0] + rowpart[t][1];
}

// ---------------- kernel 4: dual softmax + combine + renormalize ----------------
__device__ __forceinline__ float blockMax(float v, float* sm) {
    #pragma unroll
    for (int o = 32; o; o >>= 1) v = fmaxf(v, __shfl_xor(v, o));
    if ((threadIdx.x & 63) == 0) sm[threadIdx.x >> 6] = v;
    __syncthreads();
    v = fmaxf(fmaxf(sm[0], sm[1]), fmaxf(sm[2], sm[3]));
    __syncthreads();
    return v;
}
__device__ __forceinline__ float blockSum(float v, float* sm) {
    #pragma unroll
    for (int o = 32; o; o >>= 1) v += __shfl_xor(v, o);
    if ((threadIdx.x & 63) == 0) sm[threadIdx.x >> 6] = v;
    __syncthreads();
    v = sm[0] + sm[1] + sm[2] + sm[3];
    __syncthreads();
    return v;
}

__global__ __launch_bounds__(256) void softmax_combine_kernel(
    const float* __restrict__ Lp,
    float* __restrict__ wfin, float* __restrict__ dout)
{
    __shared__ float sm[4];
    int b = blockIdx.x, t = threadIdx.x;
    float h0 = 0.f, h1 = 0.f, f0 = 0.f, f1 = 0.f;
    #pragma unroll
    for (int nc = 0; nc < 8; ++nc) {
        h0 += Lp[nc * 32768 + b * 512 + t];
        h1 += Lp[nc * 32768 + b * 512 + 256 + t];
        f0 += Lp[(8 + nc) * 32768 + b * 512 + t];
        f1 += Lp[(8 + nc) * 32768 + b * 512 + 256 + t];
    }
    float mh = blockMax(fmaxf(h0, h1), sm);
    float mf = blockMax(fmaxf(f0, f1), sm);
    float e0 = __expf(h0 - mh), e1 = __expf(h1 - mh);
    float q0 = __expf(f0 - mf), q1 = __expf(f1 - mf);
    float sh = blockSum(e0 + e1, sm);
    float sf = blockSum(q0 + q1, sm);
    float wh0 = e0 / (EPS + sh), wh1 = e1 / (EPS + sh);
    float wq0 = q0 / (EPS + sf), wq1 = q1 / (EPS + sf);
    float c0 = wh0 * wq0, c1 = wh1 * wq1;
    float sc = blockSum(c0 + c1, sm);
    float r0 = c0 / (EPS + sc), r1 = c1 / (EPS + sc);
    wfin[b * 512 + t]       = r0;
    wfin[b * 512 + 256 + t] = r1;
    dout[65536 + t * 64 + b]         = r0;
    dout[65536 + (256 + t) * 64 + b] = r1;
}

// ---------------- kernel 5: context partials (fp32 hidden) ----------------
__global__ __launch_bounds__(256) void context_kernel(
    const float* __restrict__ hs, const float* __restrict__ wgt,
    float* __restrict__ ctxpart)
{
    int dq = blockIdx.x;   // 0..3
    int b  = blockIdx.y;   // 0..63
    int sh = blockIdx.z;   // 0..1
    int t = threadIdx.x;
    int ss = t >> 6, ds = t & 63;
    __shared__ float4 part[4][64];
    const float4* hp = (const float4*)hs;
    float ax = 0.f, ay = 0.f, az = 0.f, aw = 0.f;
    int sBase = sh * 256 + ss * 64;
    for (int i = 0; i < 64; ++i) {
        int s = sBase + i;
        float w = wgt[b * 512 + s];
        float4 v = hp[(size_t)(b * 512 + s) * 256 + dq * 64 + ds];
        ax += v.x * w; ay += v.y * w; az += v.z * w; aw += v.w * w;
    }
    float4 r; r.x = ax; r.y = ay; r.z = az; r.w = aw;
    part[ss][ds] = r;
    __syncthreads();
    if (ss == 0) {
        float4 a0 = part[0][ds], a1 = part[1][ds], a2 = part[2][ds], a3 = part[3][ds];
        float4 o;
        o.x = a0.x + a1.x + a2.x + a3.x;
        o.y = a0.y + a1.y + a2.y + a3.y;
        o.z = a0.z + a1.z + a2.z + a3.z;
        o.w = a0.w + a1.w + a2.w + a3.w;
        ((float4*)ctxpart)[(size_t)sh * 16384 + b * 256 + dq * 64 + ds] = o;
    }
}

// ---------------- kernel 6: out GEMV ----------------
__global__ __launch_bounds__(256) void out_kernel(
    const float* __restrict__ ctxpart, const float* __restrict__ inp,
    const float* __restrict__ W3, const float* __restrict__ b3,
    const unsigned char* __restrict__ fin, float* __restrict__ out)
{
    int t = threadIdx.x, wid = t >> 6, lane = t & 63;
    int h = blockIdx.x * 4 + wid;
    __shared__ __align__(16) float xs[2048];
    float4* xsv = (float4*)xs;
    float4 wreg[8];
    const float4* w3r = (const float4*)(W3 + (size_t)h * 2048);
    #pragma unroll
    for (int j = 0; j < 8; ++j) wreg[j] = w3r[lane + 64 * j];
    const float4* cp = (const float4*)ctxpart;
    const float4* xp = (const float4*)inp;
    for (int b = 0; b < 64; ++b) {
        __syncthreads();
        {
            float4 c0 = cp[b * 256 + t];
            float4 c1 = cp[16384 + b * 256 + t];
            float4 cc; cc.x = c0.x + c1.x; cc.y = c0.y + c1.y;
            cc.z = c0.z + c1.z; cc.w = c0.w + c1.w;
            xsv[t] = cc;
            xsv[256 + t] = xp[b * 256 + t];
        }
        __syncthreads();
        float acc = 0.f;
        #pragma unroll
        for (int j = 0; j < 8; ++j) {
            float4 x = xsv[lane + 64 * j];
            acc += wreg[j].x * x.x + wreg[j].y * x.y + wreg[j].z * x.z + wreg[j].w * x.w;
        }
        #pragma unroll
        for (int o = 32; o; o >>= 1) acc += __shfl_xor(acc, o);
        if (lane == 0) out[b * 1024 + h] = fin[b] ? 0.f : (acc + b3[h]);
    }
}

extern "C" void kernel_launch(void* const* d_in, const int* in_sizes, int n_in,
                              void* d_out, int out_size, void* d_ws, size_t ws_size,
                              hipStream_t stream)
{
    const float* hidden = (const float*)d_in[0];
    const float* field  = (const float*)d_in[1];
    const float* input  = (const float*)d_in[2];
    const unsigned char* fin = (const unsigned char*)d_in[3];
    const float* W1 = (const float*)d_in[4];
    const float* b1 = (const float*)d_in[5];
    const float* W2 = (const float*)d_in[6];
    const float* b2 = (const float*)d_in[7];
    const float* W3 = (const float*)d_in[8];
    const float* b3 = (const float*)d_in[9];
    const float* W4 = (const float*)d_in[10];
    const float* b4 = (const float*)d_in[11];
    const float* W5 = (const float*)d_in[12];
    const float* b5 = (const float*)d_in[13];
    float* out = (float*)d_out;

    char* ws = (char*)d_ws;
    float* Lpart = (float*)(ws);             // [2][8][32768] f32 = 2 MB
    float* wfin  = (float*)(ws + 2097152);   // 128 KB
    float* gamm  = (float*)(ws + 2228224);   // 256 KB
    float* alph  = (float*)(ws + 2490368);   // 256 KB
    float* ctxp  = (float*)(ws + 2752512);   // 512 KB
    f16*   Wh    = (f16*)(ws + 3276800);     // 2 * 1 Mi f16 = 4 MB

    convw_kernel<<<512, 256, 0, stream>>>(
        (const float4*)W1, (const float4*)W4,
        (f16x4*)Wh, (f16x4*)(Wh + 1048576));

    gamal_kernel<<<dim3(2048, 2), 256, 0, stream>>>(input, W2, b2, W5, b5, gamm, alph);
    gemm_logits_kernel<<<4096, 256, 0, stream>>>(hidden, field, Wh, b1, b4, gamm, alph, Lpart);
    softmax_combine_kernel<<<64, 256, 0, stream>>>(Lpart, wfin, out);
    context_kernel<<<dim3(4, 64, 2), 256, 0, stream>>>(hidden, wfin, ctxp);
    out_kernel<<<256, 256, 0, stream>>>(ctxp, input, W3, b3, fin, out);
}

// Round 10
// 323.848 us; speedup vs baseline: 1.3777x; 1.3777x over previous
//
#include <hip/hip_runtime.h>

#define EPS 1e-6f

typedef _Float16 f16;
typedef _Float16 f16x4 __attribute__((ext_vector_type(4)));
typedef _Float16 f16x8 __attribute__((ext_vector_type(8)));
typedef float f32x4 __attribute__((ext_vector_type(4)));

__device__ __forceinline__ float tanh_fast(float x) {
    float e = __expf(2.0f * x);
    return 1.0f - 2.0f / (e + 1.0f);
}

// ---------------- kernel 1: all fp32 -> f16 conversions in one launch ----------------
__global__ __launch_bounds__(256) void convall_kernel(
    const float4* __restrict__ hidden, const float4* __restrict__ field,
    const float4* __restrict__ W1, const float4* __restrict__ W4,
    f16x4* __restrict__ Ah, f16x4* __restrict__ Af,
    f16x4* __restrict__ Wh1, f16x4* __restrict__ Wh4)
{
    const int stride = gridDim.x * 256;
    for (int i = blockIdx.x * 256 + threadIdx.x; i < 17301504; i += stride) {
        const float4* s; f16x4* d; int off;
        if (i < 8388608)       { s = hidden; d = Ah;  off = i; }
        else if (i < 16777216) { s = field;  d = Af;  off = i - 8388608; }
        else if (i < 17039360) { s = W1;     d = Wh1; off = i - 16777216; }
        else                   { s = W4;     d = Wh4; off = i - 17039360; }
        float4 v = s[off];
        f16x4 o; o[0]=(f16)v.x; o[1]=(f16)v.y; o[2]=(f16)v.z; o[3]=(f16)v.w;
        d[off] = o;
    }
}

// ---------------- kernel 2: gamma/alpha GEMVs, W-row reuse over 8 batches ----------------
__global__ __launch_bounds__(256) void gamal_kernel(
    const float* __restrict__ inp,
    const float* __restrict__ W2, const float* __restrict__ b2,
    const float* __restrict__ W5, const float* __restrict__ b5,
    float* __restrict__ gamm, float* __restrict__ alph)
{
    const float* W  = blockIdx.y ? W5 : W2;
    const float* bs = blockIdx.y ? b5 : b2;
    float* dst      = blockIdx.y ? alph : gamm;
    int wid = threadIdx.x >> 6, lane = threadIdx.x & 63;
    int hb = blockIdx.x >> 3;          // 0..255
    int bb = blockIdx.x & 7;           // 0..7
    int h = hb * 4 + wid;
    int b0 = bb * 8;
    const float4* wr = (const float4*)(W + (size_t)h * 1024);
    float4 wreg[4];
    #pragma unroll
    for (int j = 0; j < 4; ++j) wreg[j] = wr[lane + 64 * j];
    float bias = bs[h];
    for (int b = b0; b < b0 + 8; ++b) {
        const float4* xr = (const float4*)(inp + (size_t)b * 1024);
        float acc = 0.f;
        #pragma unroll
        for (int j = 0; j < 4; ++j) {
            float4 x4 = xr[lane + 64 * j];
            acc += wreg[j].x * x4.x + wreg[j].y * x4.y + wreg[j].z * x4.z + wreg[j].w * x4.w;
        }
        #pragma unroll
        for (int o = 32; o; o >>= 1) acc += __shfl_xor(acc, o);
        if (lane == 0) dst[b * 1024 + h] = tanh_fast(acc + bias);
    }
}

// ---------------- kernel 3: 128x128xK1024 f16 GEMM (round-6 exact, measured 170us) ----------------
__global__ __launch_bounds__(256, 4) void gemm_logits_kernel(
    const f16* __restrict__ Ah,      // [2][32768][1024] f16 (hidden, field)
    const f16* __restrict__ Wh,      // [2][1024][1024] f16 (W1, W4)
    const float* __restrict__ b1, const float* __restrict__ b4,
    const float* __restrict__ gamm, const float* __restrict__ alph,
    float* __restrict__ Lpart)       // [2][8][32768]
{
    __shared__ __align__(16) char smA[16384];   // 128 rows x 128 B
    __shared__ __align__(16) char smW[16384];
    __shared__ float rowpart[128][2];

    const int lin = blockIdx.x;
    const int gidx = (lin & 7) * 512 + (lin >> 3);   // XCD swizzle, bijective
    const int mat = gidx >> 11;
    const int rem = gidx & 2047;
    const int m_blk = rem >> 3;
    const int nc = rem & 7;
    const int m0 = m_blk << 7;
    const int hc0 = nc << 7;
    const int bidx = m_blk >> 2;

    const f16* A   = Ah + (size_t)mat * 33554432;
    const f16* W   = Wh + (size_t)mat * 1048576;
    const float* bv = mat ? b4 : b1;
    const float* gv = mat ? alph : gamm;

    const int t = threadIdx.x;
    const int lane = t & 63;
    const int wv = t >> 6;       // 0..3
    const int wr = wv >> 1;      // 0..1
    const int wc = wv & 1;       // 0..1
    const int c16 = lane & 15;
    const int kg = lane >> 4;

    const int lrow = lane >> 3, lslot = lane & 7;
    const int kchunk = lslot ^ lrow;

    const int swzr = (c16 & 7) << 4;
    const int aoffb = (wr * 64 + c16) * 128;
    const int woffb = (wc * 64 + c16) * 128;
    const int kg16 = kg * 16;

    f32x4 acc[4][4];
    #pragma unroll
    for (int i = 0; i < 4; ++i)
        #pragma unroll
        for (int j = 0; j < 4; ++j) acc[i][j] = (f32x4){0.f, 0.f, 0.f, 0.f};

    for (int kt = 0; kt < 16; ++kt) {
        #pragma unroll
        for (int j = 0; j < 4; ++j) {
            int r = wv * 32 + j * 8;
            const f16* srcA = A + (size_t)(m0 + r + lrow) * 1024 + kt * 64 + kchunk * 8;
            __builtin_amdgcn_global_load_lds(
                (const __attribute__((address_space(1))) void*)srcA,
                (__attribute__((address_space(3))) void*)(smA + r * 128), 16, 0, 0);
        }
        #pragma unroll
        for (int j = 0; j < 4; ++j) {
            int r = wv * 32 + j * 8;
            const f16* srcW = W + (size_t)(hc0 + r + lrow) * 1024 + kt * 64 + kchunk * 8;
            __builtin_amdgcn_global_load_lds(
                (const __attribute__((address_space(1))) void*)srcW,
                (__attribute__((address_space(3))) void*)(smW + r * 128), 16, 0, 0);
        }
        __syncthreads();

        #pragma unroll
        for (int kk = 0; kk < 2; ++kk) {
            const int ko = (kk * 64 + kg16) ^ swzr;
            f16x8 af[4], wf[4];
            #pragma unroll
            for (int i = 0; i < 4; ++i) af[i] = *(const f16x8*)(smA + aoffb + i * 2048 + ko);
            #pragma unroll
            for (int i = 0; i < 4; ++i) wf[i] = *(const f16x8*)(smW + woffb + i * 2048 + ko);
            #pragma unroll
            for (int ni = 0; ni < 4; ++ni)
                #pragma unroll
                for (int mi = 0; mi < 4; ++mi)
                    acc[mi][ni] = __builtin_amdgcn_mfma_f32_16x16x32_f16(af[mi], wf[ni], acc[mi][ni], 0, 0, 0);
        }
        __syncthreads();
    }

    // ---- epilogue: tanh + gamma-dot ----
    float g[4], bb[4];
    #pragma unroll
    for (int ni = 0; ni < 4; ++ni) {
        int h = hc0 + wc * 64 + ni * 16 + c16;
        g[ni]  = gv[(bidx << 10) + h];
        bb[ni] = bv[h];
    }
    #pragma unroll
    for (int mi = 0; mi < 4; ++mi) {
        #pragma unroll
        for (int q = 0; q < 4; ++q) {
            float v = tanh_fast(acc[mi][0][q] + bb[0]) * g[0]
                    + tanh_fast(acc[mi][1][q] + bb[1]) * g[1]
                    + tanh_fast(acc[mi][2][q] + bb[2]) * g[2]
                    + tanh_fast(acc[mi][3][q] + bb[3]) * g[3];
            v += __shfl_xor(v, 1);
            v += __shfl_xor(v, 2);
            v += __shfl_xor(v, 4);
            v += __shfl_xor(v, 8);
            if (c16 == 0)
                rowpart[wr * 64 + mi * 16 + kg * 4 + q][wc] = v;
        }
    }
    __syncthreads();
    if (t < 128)
        Lpart[(size_t)(mat * 8 + nc) * 32768 + m0 + t] = rowpart[t][0] + rowpart[t][1];
}

// ---------------- kernel 4: dual softmax + combine + renormalize ----------------
__device__ __forceinline__ float blockMax(float v, float* sm) {
    #pragma unroll
    for (int o = 32; o; o >>= 1) v = fmaxf(v, __shfl_xor(v, o));
    if ((threadIdx.x & 63) == 0) sm[threadIdx.x >> 6] = v;
    __syncthreads();
    v = fmaxf(fmaxf(sm[0], sm[1]), fmaxf(sm[2], sm[3]));
    __syncthreads();
    return v;
}
__device__ __forceinline__ float blockSum(float v, float* sm) {
    #pragma unroll
    for (int o = 32; o; o >>= 1) v += __shfl_xor(v, o);
    if ((threadIdx.x & 63) == 0) sm[threadIdx.x >> 6] = v;
    __syncthreads();
    v = sm[0] + sm[1] + sm[2] + sm[3];
    __syncthreads();
    return v;
}

__global__ __launch_bounds__(256) void softmax_combine_kernel(
    const float* __restrict__ Lp,
    float* __restrict__ wfin, float* __restrict__ dout)
{
    __shared__ float sm[4];
    int b = blockIdx.x, t = threadIdx.x;
    float h0 = 0.f, h1 = 0.f, f0 = 0.f, f1 = 0.f;
    #pragma unroll
    for (int nc = 0; nc < 8; ++nc) {
        h0 += Lp[nc * 32768 + b * 512 + t];
        h1 += Lp[nc * 32768 + b * 512 + 256 + t];
        f0 += Lp[(8 + nc) * 32768 + b * 512 + t];
        f1 += Lp[(8 + nc) * 32768 + b * 512 + 256 + t];
    }
    float mh = blockMax(fmaxf(h0, h1), sm);
    float mf = blockMax(fmaxf(f0, f1), sm);
    float e0 = __expf(h0 - mh), e1 = __expf(h1 - mh);
    float q0 = __expf(f0 - mf), q1 = __expf(f1 - mf);
    float sh = blockSum(e0 + e1, sm);
    float sf = blockSum(q0 + q1, sm);
    float wh0 = e0 / (EPS + sh), wh1 = e1 / (EPS + sh);
    float wq0 = q0 / (EPS + sf), wq1 = q1 / (EPS + sf);
    float c0 = wh0 * wq0, c1 = wh1 * wq1;
    float sc = blockSum(c0 + c1, sm);
    float r0 = c0 / (EPS + sc), r1 = c1 / (EPS + sc);
    wfin[b * 512 + t]       = r0;
    wfin[b * 512 + 256 + t] = r1;
    dout[65536 + t * 64 + b]         = r0;
    dout[65536 + (256 + t) * 64 + b] = r1;
}

// ---------------- kernel 5: context partials from the f16 hidden copy ----------------
__global__ __launch_bounds__(256) void context_kernel(
    const f16* __restrict__ Ah, const float* __restrict__ wgt,
    float* __restrict__ ctxpart)
{
    int dq = blockIdx.x;   // 0..1
    int b  = blockIdx.y;   // 0..63
    int sh = blockIdx.z;   // 0..1
    int t = threadIdx.x;
    int ss = t >> 6, ds = t & 63;
    __shared__ float part[4][64][8];
    float a[8] = {0,0,0,0,0,0,0,0};
    int sBase = sh * 256 + ss * 64;
    const f16* hp = Ah + (size_t)b * 524288 + dq * 512 + ds * 8;
    for (int i = 0; i < 64; ++i) {
        int s = sBase + i;
        float w = wgt[b * 512 + s];
        f16x8 v = *(const f16x8*)(hp + (size_t)s * 1024);
        #pragma unroll
        for (int j = 0; j < 8; ++j) a[j] += w * (float)v[j];
    }
    #pragma unroll
    for (int j = 0; j < 8; ++j) part[ss][ds][j] = a[j];
    __syncthreads();
    if (ss == 0) {
        #pragma unroll
        for (int j = 0; j < 8; ++j) {
            float o = part[0][ds][j] + part[1][ds][j] + part[2][ds][j] + part[3][ds][j];
            ctxpart[(size_t)sh * 65536 + b * 1024 + dq * 512 + ds * 8 + j] = o;
        }
    }
}

// ---------------- kernel 6: out GEMV ----------------
__global__ __launch_bounds__(256) void out_kernel(
    const float* __restrict__ ctxpart, const float* __restrict__ inp,
    const float* __restrict__ W3, const float* __restrict__ b3,
    const unsigned char* __restrict__ fin, float* __restrict__ out)
{
    int t = threadIdx.x, wid = t >> 6, lane = t & 63;
    int h = blockIdx.x * 4 + wid;
    __shared__ __align__(16) float xs[2048];
    float4* xsv = (float4*)xs;
    float4 wreg[8];
    const float4* w3r = (const float4*)(W3 + (size_t)h * 2048);
    #pragma unroll
    for (int j = 0; j < 8; ++j) wreg[j] = w3r[lane + 64 * j];
    const float4* cp = (const float4*)ctxpart;
    const float4* xp = (const float4*)inp;
    for (int b = 0; b < 64; ++b) {
        __syncthreads();
        {
            float4 c0 = cp[b * 256 + t];
            float4 c1 = cp[16384 + b * 256 + t];
            float4 cc; cc.x = c0.x + c1.x; cc.y = c0.y + c1.y;
            cc.z = c0.z + c1.z; cc.w = c0.w + c1.w;
            xsv[t] = cc;
            xsv[256 + t] = xp[b * 256 + t];
        }
        __syncthreads();
        float acc = 0.f;
        #pragma unroll
        for (int j = 0; j < 8; ++j) {
            float4 x = xsv[lane + 64 * j];
            acc += wreg[j].x * x.x + wreg[j].y * x.y + wreg[j].z * x.z + wreg[j].w * x.w;
        }
        #pragma unroll
        for (int o = 32; o; o >>= 1) acc += __shfl_xor(acc, o);
        if (lane == 0) out[b * 1024 + h] = fin[b] ? 0.f : (acc + b3[h]);
    }
}

extern "C" void kernel_launch(void* const* d_in, const int* in_sizes, int n_in,
                              void* d_out, int out_size, void* d_ws, size_t ws_size,
                              hipStream_t stream)
{
    const float* hidden = (const float*)d_in[0];
    const float* field  = (const float*)d_in[1];
    const float* input  = (const float*)d_in[2];
    const unsigned char* fin = (const unsigned char*)d_in[3];
    const float* W1 = (const float*)d_in[4];
    const float* b1 = (const float*)d_in[5];
    const float* W2 = (const float*)d_in[6];
    const float* b2 = (const float*)d_in[7];
    const float* W3 = (const float*)d_in[8];
    const float* b3 = (const float*)d_in[9];
    const float* W4 = (const float*)d_in[10];
    const float* b4 = (const float*)d_in[11];
    const float* W5 = (const float*)d_in[12];
    const float* b5 = (const float*)d_in[13];
    float* out = (float*)d_out;

    char* ws = (char*)d_ws;
    float* Lpart = (float*)(ws);             // [2][8][32768] f32 = 2 MB
    float* wfin  = (float*)(ws + 2097152);   // 128 KB
    float* gamm  = (float*)(ws + 2228224);   // 256 KB
    float* alph  = (float*)(ws + 2490368);   // 256 KB
    float* ctxp  = (float*)(ws + 2752512);   // 512 KB
    f16*   Wh    = (f16*)(ws + 3276800);     // 2 * 1 Mi f16 = 4 MB
    f16*   Ah    = (f16*)(ws + 7471104);     // 2 * 32 Mi f16 = 128 MB

    convall_kernel<<<8192, 256, 0, stream>>>(
        (const float4*)hidden, (const float4*)field,
        (const float4*)W1, (const float4*)W4,
        (f16x4*)Ah, (f16x4*)(Ah + 33554432),
        (f16x4*)Wh, (f16x4*)(Wh + 1048576));

    gamal_kernel<<<dim3(2048, 2), 256, 0, stream>>>(input, W2, b2, W5, b5, gamm, alph);
    gemm_logits_kernel<<<4096, 256, 0, stream>>>(Ah, Wh, b1, b4, gamm, alph, Lpart);
    softmax_combine_kernel<<<64, 256, 0, stream>>>(Lpart, wfin, out);
    context_kernel<<<dim3(2, 64, 2), 256, 0, stream>>>(Ah, wfin, ctxp);
    out_kernel<<<256, 256, 0, stream>>>(ctxp, input, W3, b3, fin, out);
}